// Round 2
// baseline (359.383 us; speedup 1.0000x reference)
//
#include <hip/hip_runtime.h>
#include <hip/hip_bf16.h>

#define NROWS 65536
#define DFEAT 256

__device__ __forceinline__ float fast_tanh(float x) {
    // stable both directions: exp->inf gives 1, exp->0 gives -1 (no NaN)
    return 1.0f - 2.0f / (__expf(2.0f * x) + 1.0f);
}

// ---------------------------------------------------------------------------
// Kernel 1: per-column sum and sum-of-squares over x [65536, 256]
// grid 512 blocks x 256 threads; each block handles 128 rows; float4 loads.
// ---------------------------------------------------------------------------
__global__ void stats_kernel(const float4* __restrict__ x4,
                             float* __restrict__ sums,
                             float* __restrict__ sumsq) {
    __shared__ float ps[4][256];
    __shared__ float pq[4][256];
    int t = threadIdx.x;
    int c4 = t & 63;   // float4 column group 0..63
    int r  = t >> 6;   // 0..3
    size_t i0 = (size_t)blockIdx.x * 128;
    float4 s = make_float4(0.f, 0.f, 0.f, 0.f);
    float4 q = make_float4(0.f, 0.f, 0.f, 0.f);
    for (int i = r; i < 128; i += 4) {
        float4 v = x4[(i0 + i) * 64 + c4];
        s.x += v.x; s.y += v.y; s.z += v.z; s.w += v.w;
        q.x += v.x * v.x; q.y += v.y * v.y; q.z += v.z * v.z; q.w += v.w * v.w;
    }
    ps[r][c4 * 4 + 0] = s.x; ps[r][c4 * 4 + 1] = s.y;
    ps[r][c4 * 4 + 2] = s.z; ps[r][c4 * 4 + 3] = s.w;
    pq[r][c4 * 4 + 0] = q.x; pq[r][c4 * 4 + 1] = q.y;
    pq[r][c4 * 4 + 2] = q.z; pq[r][c4 * 4 + 3] = q.w;
    __syncthreads();
    float ts = ps[0][t] + ps[1][t] + ps[2][t] + ps[3][t];
    float tq = pq[0][t] + pq[1][t] + pq[2][t] + pq[3][t];
    atomicAdd(&sums[t], ts);
    atomicAdd(&sumsq[t], tq);
}

// ---------------------------------------------------------------------------
// Kernel 2: finalize BN params -> xn = x*scl[k] + sft[k]
// ---------------------------------------------------------------------------
__global__ void finalize_kernel(const float* __restrict__ sums,
                                const float* __restrict__ sumsq,
                                const float* __restrict__ gamma,
                                const float* __restrict__ beta,
                                float* __restrict__ scl,
                                float* __restrict__ sft) {
    int t = threadIdx.x;
    const float invN = 1.0f / (float)NROWS;
    float mu  = sums[t] * invN;
    float var = sumsq[t] * invN - mu * mu;
    float rs  = rsqrtf(var + 1e-5f);
    float a   = gamma[t] * rs;
    scl[t] = a;
    sft[t] = beta[t] - mu * a;
}

// ---------------------------------------------------------------------------
// Kernel 3: mat-vec  out[r] = dot(W[r,:K], vin) + badd[r]
// one 64-lane wave per row, 4 rows per block.
// ---------------------------------------------------------------------------
__global__ void matvec_kernel(const float* __restrict__ W,
                              const float* __restrict__ vin,
                              const float* __restrict__ badd,
                              float* __restrict__ outv,
                              int K) {
    int t = threadIdx.x;
    int lane = t & 63;
    int row = blockIdx.x * 4 + (t >> 6);
    const float* Wr = W + (size_t)row * K;
    float s = 0.f;
    for (int k = lane; k < K; k += 64) s += Wr[k] * vin[k];
    #pragma unroll
    for (int off = 32; off; off >>= 1) s += __shfl_xor(s, off);
    if (lane == 0) outv[row] = s + badd[row];
}

// ---------------------------------------------------------------------------
// Kernel 4: small fp32 tiled GEMM with split-K, C += A[M,K] @ B[K,N] chunk.
// 32x32 tile, 256 threads, 2x2 per thread. blockIdx.z picks the K chunk;
// results accumulated into pre-zeroed C via atomicAdd (fp32).
// TRANS_OUT stores C[j*M+i] (i.e. C = result^T).
// ---------------------------------------------------------------------------
template <bool TRANS_OUT>
__global__ void gemm_tile32_atomic(const float* __restrict__ A,
                                   const float* __restrict__ B,
                                   float* __restrict__ C,
                                   int M, int N, int K, int Kc) {
    __shared__ float As[32][33];
    __shared__ float Bs[32][33];
    int t = threadIdx.x;
    int tx = t & 15, ty = t >> 4;
    int bi = blockIdx.y * 32;
    int bj = blockIdx.x * 32;
    int kb = blockIdx.z * Kc;
    int row = t >> 3;            // 0..31
    int col = (t & 7) * 4;       // 0..28
    float acc00 = 0.f, acc01 = 0.f, acc10 = 0.f, acc11 = 0.f;
    for (int k0 = kb; k0 < kb + Kc; k0 += 32) {
        float4 av = *(const float4*)&A[(size_t)(bi + row) * K + k0 + col];
        As[row][col + 0] = av.x; As[row][col + 1] = av.y;
        As[row][col + 2] = av.z; As[row][col + 3] = av.w;
        float4 bv = *(const float4*)&B[(size_t)(k0 + row) * N + bj + col];
        Bs[row][col + 0] = bv.x; Bs[row][col + 1] = bv.y;
        Bs[row][col + 2] = bv.z; Bs[row][col + 3] = bv.w;
        __syncthreads();
        #pragma unroll
        for (int k = 0; k < 32; ++k) {
            float a0 = As[ty * 2 + 0][k];
            float a1 = As[ty * 2 + 1][k];
            float b0 = Bs[k][tx * 2 + 0];
            float b1 = Bs[k][tx * 2 + 1];
            acc00 += a0 * b0; acc01 += a0 * b1;
            acc10 += a1 * b0; acc11 += a1 * b1;
        }
        __syncthreads();
    }
    int i = bi + ty * 2, j = bj + tx * 2;
    if (TRANS_OUT) {
        atomicAdd(&C[(size_t)(j + 0) * M + i + 0], acc00);
        atomicAdd(&C[(size_t)(j + 1) * M + i + 0], acc01);
        atomicAdd(&C[(size_t)(j + 0) * M + i + 1], acc10);
        atomicAdd(&C[(size_t)(j + 1) * M + i + 1], acc11);
    } else {
        atomicAdd(&C[(size_t)(i + 0) * N + j + 0], acc00);
        atomicAdd(&C[(size_t)(i + 0) * N + j + 1], acc01);
        atomicAdd(&C[(size_t)(i + 1) * N + j + 0], acc10);
        atomicAdd(&C[(size_t)(i + 1) * N + j + 1], acc11);
    }
}

// ---------------------------------------------------------------------------
// Kernel 5 (main, fused): per 64-row block:
//   xn = x*scl+sft (staged to LDS), raw_feats = tanh(xn) written out,
//   out = tanh(xn @ Mt + c)  with Mt[k][j] = M[j][k] (combined weights).
// BM=64 rows, BN=256 (all cols), BK=32, 256 threads, 8x8 per-thread tile.
// ---------------------------------------------------------------------------
__global__ __launch_bounds__(256)
void main_kernel(const float4* __restrict__ x4,
                 const float* __restrict__ scl,
                 const float* __restrict__ sft,
                 const float4* __restrict__ Mt4,
                 const float* __restrict__ cvec,
                 float4* __restrict__ out4,
                 float4* __restrict__ rf4) {
    __shared__ float At[32][68];     // [k][row], pad to 68 keeps 16B alignment
    __shared__ float Bs[32][256];    // [k][col]
    __shared__ float ss[256], sh[256], cc[256];
    int t = threadIdx.x;
    ss[t] = scl[t]; sh[t] = sft[t]; cc[t] = cvec[t];
    size_t i0 = (size_t)blockIdx.x * 64;
    int tc = t & 31;   // col group 0..31
    int tr = t >> 5;   // row group 0..7
    float acc[8][8];
    #pragma unroll
    for (int a = 0; a < 8; ++a)
        #pragma unroll
        for (int b = 0; b < 8; ++b) acc[a][b] = 0.f;
    __syncthreads();

    for (int k0 = 0; k0 < 256; k0 += 32) {
        // --- stage A (xn) + write raw_feats ---
        #pragma unroll
        for (int m = 0; m < 2; ++m) {
            int q = m * 256 + t;
            int row = q >> 3;          // 0..63
            int jj = q & 7;            // 0..7 (float4 within k-chunk)
            int kk = k0 + jj * 4;
            float4 v = x4[(i0 + row) * 64 + (kk >> 2)];
            float4 xn;
            xn.x = v.x * ss[kk + 0] + sh[kk + 0];
            xn.y = v.y * ss[kk + 1] + sh[kk + 1];
            xn.z = v.z * ss[kk + 2] + sh[kk + 2];
            xn.w = v.w * ss[kk + 3] + sh[kk + 3];
            float4 rf;
            rf.x = fast_tanh(xn.x); rf.y = fast_tanh(xn.y);
            rf.z = fast_tanh(xn.z); rf.w = fast_tanh(xn.w);
            rf4[(i0 + row) * 64 + (kk >> 2)] = rf;
            At[jj * 4 + 0][row] = xn.x;
            At[jj * 4 + 1][row] = xn.y;
            At[jj * 4 + 2][row] = xn.z;
            At[jj * 4 + 3][row] = xn.w;
        }
        // --- stage B (Mt slice) ---
        #pragma unroll
        for (int p = 0; p < 8; ++p) {
            int k = p * 4 + (t >> 6);
            int j4 = t & 63;
            float4 bv = Mt4[(size_t)(k0 + k) * 64 + j4];
            *(float4*)&Bs[k][j4 * 4] = bv;
        }
        __syncthreads();
        // --- compute ---
        #pragma unroll
        for (int k = 0; k < 32; ++k) {
            float4 a0 = *(const float4*)&At[k][tr * 8 + 0];
            float4 a1 = *(const float4*)&At[k][tr * 8 + 4];
            float4 b0 = *(const float4*)&Bs[k][tc * 4 + 0];
            float4 b1 = *(const float4*)&Bs[k][tc * 4 + 128];
            float av[8] = {a0.x, a0.y, a0.z, a0.w, a1.x, a1.y, a1.z, a1.w};
            float bv[8] = {b0.x, b0.y, b0.z, b0.w, b1.x, b1.y, b1.z, b1.w};
            #pragma unroll
            for (int a = 0; a < 8; ++a)
                #pragma unroll
                for (int b = 0; b < 8; ++b)
                    acc[a][b] += av[a] * bv[b];
        }
        __syncthreads();
    }
    // --- epilogue: out = tanh(acc + c) ---
    #pragma unroll
    for (int a = 0; a < 8; ++a) {
        int row = tr * 8 + a;
        float4 o0, o1;
        o0.x = fast_tanh(acc[a][0] + cc[tc * 4 + 0]);
        o0.y = fast_tanh(acc[a][1] + cc[tc * 4 + 1]);
        o0.z = fast_tanh(acc[a][2] + cc[tc * 4 + 2]);
        o0.w = fast_tanh(acc[a][3] + cc[tc * 4 + 3]);
        o1.x = fast_tanh(acc[a][4] + cc[tc * 4 + 128]);
        o1.y = fast_tanh(acc[a][5] + cc[tc * 4 + 129]);
        o1.z = fast_tanh(acc[a][6] + cc[tc * 4 + 130]);
        o1.w = fast_tanh(acc[a][7] + cc[tc * 4 + 131]);
        out4[(i0 + row) * 64 + tc] = o0;
        out4[(i0 + row) * 64 + tc + 32] = o1;
    }
}

// ---------------------------------------------------------------------------
// ws layout (floats):
//   [0]      sums   256
//   [256]    sumsq  256
//   [512]    P      131072   (Wf@W2, [256,512])
//   [131584] Mt     65536    ((P@W1)^T = M^T, [256,256])
//   [197120] scl    256
//   [197376] sft    256
//   [197632] u      2048
//   [199680] cv     256
// total ~800 KB. First 197120 floats must be zeroed each call (atomics).
// ---------------------------------------------------------------------------
extern "C" void kernel_launch(void* const* d_in, const int* in_sizes, int n_in,
                              void* d_out, int out_size, void* d_ws, size_t ws_size,
                              hipStream_t stream) {
    const float* x     = (const float*)d_in[0];
    const float* gamma = (const float*)d_in[1];
    const float* beta  = (const float*)d_in[2];
    const float* W1    = (const float*)d_in[3];
    const float* b1    = (const float*)d_in[4];
    const float* W2    = (const float*)d_in[5];
    const float* b2    = (const float*)d_in[6];
    const float* Wf    = (const float*)d_in[7];
    const float* bf    = (const float*)d_in[8];

    float* out = (float*)d_out;                    // [65536,256]
    float* rf  = out + (size_t)NROWS * DFEAT;      // [65536,256]

    float* ws    = (float*)d_ws;
    float* sums  = ws;                 // 256
    float* sumsq = ws + 256;           // 256
    float* P     = ws + 512;           // [256,512]
    float* Mt    = ws + 512 + 131072;  // [256,256]
    float* scl   = ws + 197120;        // 256
    float* sft   = ws + 197376;        // 256
    float* u     = ws + 197632;        // 2048
    float* cv    = ws + 199680;        // 256

    // zero the atomic-accumulated region: sums, sumsq, P, Mt (contiguous)
    hipMemsetAsync(ws, 0, (size_t)197120 * sizeof(float), stream);

    // BN stats over x
    stats_kernel<<<512, 256, 0, stream>>>((const float4*)x, sums, sumsq);
    finalize_kernel<<<1, 256, 0, stream>>>(sums, sumsq, gamma, beta, scl, sft);

    // bias chain: u = W2@b1 + b2 [2048] ; cv = Wf@u + bf [256]
    matvec_kernel<<<512, 256, 0, stream>>>(W2, b1, b2, u, 512);
    matvec_kernel<<<64, 256, 0, stream>>>(Wf, u, bf, cv, 2048);

    // weight collapse: P = Wf@W2  [256,512], K=2048, split-K 8x256
    gemm_tile32_atomic<false><<<dim3(512 / 32, 256 / 32, 8), 256, 0, stream>>>(
        Wf, W2, P, 256, 512, 2048, 256);
    // Mt = (P@W1)^T  [256,256], K=512, split-K 4x128
    gemm_tile32_atomic<true><<<dim3(256 / 32, 256 / 32, 4), 256, 0, stream>>>(
        P, W1, Mt, 256, 256, 512, 128);

    // fused BN + raw_feats + collapsed GEMM + tanh
    main_kernel<<<NROWS / 64, 256, 0, stream>>>((const float4*)x, scl, sft,
                                                (const float4*)Mt, cv,
                                                (float4*)out, (float4*)rf);
}

// Round 3
// 285.460 us; speedup vs baseline: 1.2590x; 1.2590x over previous
//
#include <hip/hip_runtime.h>
#include <hip/hip_bf16.h>
#include <stdint.h>

#define NROWS 65536
#define DFEAT 256

typedef __bf16 bf16x8 __attribute__((ext_vector_type(8)));
typedef float f32x4 __attribute__((ext_vector_type(4)));

__device__ __forceinline__ float fast_tanh(float x) {
    return 1.0f - 2.0f / (__expf(2.0f * x) + 1.0f);
}

__device__ __forceinline__ void gload_lds16(const void* g, void* l) {
    __builtin_amdgcn_global_load_lds(
        (const __attribute__((address_space(1))) unsigned int*)g,
        (__attribute__((address_space(3))) unsigned int*)l, 16, 0, 0);
}

// ---------------------------------------------------------------------------
// Kernel 1: per-column sum and sum-of-squares over x [65536, 256]
// ---------------------------------------------------------------------------
__global__ void stats_kernel(const float4* __restrict__ x4,
                             float* __restrict__ sums,
                             float* __restrict__ sumsq) {
    __shared__ float ps[4][256];
    __shared__ float pq[4][256];
    int t = threadIdx.x;
    int c4 = t & 63;
    int r  = t >> 6;
    size_t i0 = (size_t)blockIdx.x * 128;
    float4 s = make_float4(0.f, 0.f, 0.f, 0.f);
    float4 q = make_float4(0.f, 0.f, 0.f, 0.f);
    for (int i = r; i < 128; i += 4) {
        float4 v = x4[(i0 + i) * 64 + c4];
        s.x += v.x; s.y += v.y; s.z += v.z; s.w += v.w;
        q.x += v.x * v.x; q.y += v.y * v.y; q.z += v.z * v.z; q.w += v.w * v.w;
    }
    ps[r][c4 * 4 + 0] = s.x; ps[r][c4 * 4 + 1] = s.y;
    ps[r][c4 * 4 + 2] = s.z; ps[r][c4 * 4 + 3] = s.w;
    pq[r][c4 * 4 + 0] = q.x; pq[r][c4 * 4 + 1] = q.y;
    pq[r][c4 * 4 + 2] = q.z; pq[r][c4 * 4 + 3] = q.w;
    __syncthreads();
    float ts = ps[0][t] + ps[1][t] + ps[2][t] + ps[3][t];
    float tq = pq[0][t] + pq[1][t] + pq[2][t] + pq[3][t];
    atomicAdd(&sums[t], ts);
    atomicAdd(&sumsq[t], tq);
}

// ---------------------------------------------------------------------------
// Kernel 2: block 0 -> finalize BN scale/shift; blocks 1..512 -> u = W2@b1+b2
// ---------------------------------------------------------------------------
__global__ void finalize_mvu_kernel(const float* __restrict__ sums,
                                    const float* __restrict__ sumsq,
                                    const float* __restrict__ gamma,
                                    const float* __restrict__ beta,
                                    float* __restrict__ scl,
                                    float* __restrict__ sft,
                                    const float* __restrict__ W2,
                                    const float* __restrict__ b1,
                                    const float* __restrict__ b2,
                                    float* __restrict__ u) {
    int t = threadIdx.x;
    if (blockIdx.x == 0) {
        const float invN = 1.0f / (float)NROWS;
        float mu  = sums[t] * invN;
        float var = sumsq[t] * invN - mu * mu;
        float rs  = rsqrtf(var + 1e-5f);
        float a   = gamma[t] * rs;
        scl[t] = a;
        sft[t] = beta[t] - mu * a;
        return;
    }
    int lane = t & 63;
    int row = (blockIdx.x - 1) * 4 + (t >> 6);
    const float* Wr = W2 + (size_t)row * 512;
    float s = 0.f;
    for (int k = lane; k < 512; k += 64) s += Wr[k] * b1[k];
    #pragma unroll
    for (int off = 32; off; off >>= 1) s += __shfl_xor(s, off);
    if (lane == 0) u[row] = s + b2[row];
}

// ---------------------------------------------------------------------------
// Kernel 3: P = Wf@W2  [256,512], K=2048, split-K=4 with fp32 atomics.
// ---------------------------------------------------------------------------
__global__ void pgemm_kernel(const float* __restrict__ A,   // Wf [256,2048]
                             const float* __restrict__ B,   // W2 [2048,512]
                             float* __restrict__ C) {       // P  [256,512]
    __shared__ float As[32][33];
    __shared__ float Bs[32][33];
    int t = threadIdx.x;
    int tx = t & 15, ty = t >> 4;
    int bi = blockIdx.y * 32;
    int bj = blockIdx.x * 32;
    int kb = blockIdx.z * 512;
    int row = t >> 3;
    int col = (t & 7) * 4;
    float acc00 = 0.f, acc01 = 0.f, acc10 = 0.f, acc11 = 0.f;
    for (int k0 = kb; k0 < kb + 512; k0 += 32) {
        float4 av = *(const float4*)&A[(size_t)(bi + row) * 2048 + k0 + col];
        As[row][col + 0] = av.x; As[row][col + 1] = av.y;
        As[row][col + 2] = av.z; As[row][col + 3] = av.w;
        float4 bv = *(const float4*)&B[(size_t)(k0 + row) * 512 + bj + col];
        Bs[row][col + 0] = bv.x; Bs[row][col + 1] = bv.y;
        Bs[row][col + 2] = bv.z; Bs[row][col + 3] = bv.w;
        __syncthreads();
        #pragma unroll
        for (int k = 0; k < 32; ++k) {
            float a0 = As[ty * 2 + 0][k];
            float a1 = As[ty * 2 + 1][k];
            float b0 = Bs[k][tx * 2 + 0];
            float b1v = Bs[k][tx * 2 + 1];
            acc00 += a0 * b0; acc01 += a0 * b1v;
            acc10 += a1 * b0; acc11 += a1 * b1v;
        }
        __syncthreads();
    }
    int i = bi + ty * 2, j = bj + tx * 2;
    atomicAdd(&C[(size_t)(i + 0) * 512 + j + 0], acc00);
    atomicAdd(&C[(size_t)(i + 0) * 512 + j + 1], acc01);
    atomicAdd(&C[(size_t)(i + 1) * 512 + j + 0], acc10);
    atomicAdd(&C[(size_t)(i + 1) * 512 + j + 1], acc11);
}

// ---------------------------------------------------------------------------
// Kernel 4: blocks 0..63: M = P@W1 [256j,256k], epilogue splits to bf16 hi/lo
//           in Bprep[kstep][var][kgrp][col=j][8] layout (main kernel B staging).
//           blocks 64..127: cv = Wf@u + bf.
// ---------------------------------------------------------------------------
__global__ void collapse2_kernel(const float* __restrict__ P,    // [256,512]
                                 const float* __restrict__ W1,   // [512,256]
                                 const float* __restrict__ Wf,   // [256,2048]
                                 const float* __restrict__ u,    // [2048]
                                 const float* __restrict__ bfv,  // [256]
                                 __bf16* __restrict__ Bprep,     // [8][2][4][256][8]
                                 float* __restrict__ cv) {
    __shared__ float As[32][33];
    __shared__ float Bs[32][33];
    int t = threadIdx.x;
    if (blockIdx.x >= 64) {
        int lane = t & 63;
        int row = (blockIdx.x - 64) * 4 + (t >> 6);
        const float* Wr = Wf + (size_t)row * 2048;
        float s = 0.f;
        for (int k = lane; k < 2048; k += 64) s += Wr[k] * u[k];
        #pragma unroll
        for (int off = 32; off; off >>= 1) s += __shfl_xor(s, off);
        if (lane == 0) cv[row] = s + bfv[row];
        return;
    }
    int tx = t & 15, ty = t >> 4;
    int bi = (blockIdx.x >> 3) * 32;   // j-dim of M
    int bj = (blockIdx.x & 7) * 32;    // k-dim of M
    int row = t >> 3;
    int col = (t & 7) * 4;
    float acc00 = 0.f, acc01 = 0.f, acc10 = 0.f, acc11 = 0.f;
    for (int k0 = 0; k0 < 512; k0 += 32) {
        float4 av = *(const float4*)&P[(size_t)(bi + row) * 512 + k0 + col];
        As[row][col + 0] = av.x; As[row][col + 1] = av.y;
        As[row][col + 2] = av.z; As[row][col + 3] = av.w;
        float4 bv = *(const float4*)&W1[(size_t)(k0 + row) * 256 + bj + col];
        Bs[row][col + 0] = bv.x; Bs[row][col + 1] = bv.y;
        Bs[row][col + 2] = bv.z; Bs[row][col + 3] = bv.w;
        __syncthreads();
        #pragma unroll
        for (int k = 0; k < 32; ++k) {
            float a0 = As[ty * 2 + 0][k];
            float a1 = As[ty * 2 + 1][k];
            float b0 = Bs[k][tx * 2 + 0];
            float b1v = Bs[k][tx * 2 + 1];
            acc00 += a0 * b0; acc01 += a0 * b1v;
            acc10 += a1 * b0; acc11 += a1 * b1v;
        }
        __syncthreads();
    }
    int j = bi + ty * 2, k = bj + tx * 2;
    float vals[2][2] = {{acc00, acc01}, {acc10, acc11}};
    #pragma unroll
    for (int dj = 0; dj < 2; ++dj)
        #pragma unroll
        for (int dk = 0; dk < 2; ++dk) {
            float v = vals[dj][dk];
            int jj = j + dj, kk = k + dk;
            __bf16 h = (__bf16)v;
            __bf16 lo = (__bf16)(v - (float)h);
            int kstep = kk >> 5, kgrp = (kk >> 3) & 3, e = kk & 7;
            Bprep[((((size_t)kstep * 2 + 0) * 4 + kgrp) * 256 + jj) * 8 + e] = h;
            Bprep[((((size_t)kstep * 2 + 1) * 4 + kgrp) * 256 + jj) * 8 + e] = lo;
        }
}

// ---------------------------------------------------------------------------
// Kernel 5 (main): fused BN + raw_feats + split-bf16 MFMA GEMM + tanh.
// 256 threads = 4 waves. BM=64 rows, BN=256 cols, BK=32, 8 K-steps.
// Wave w owns cols [w*64, w*64+64): 4x4 tiles of 16x16x32 bf16 MFMA.
// 3 passes: xh@Mh + xl@Mh + xh@Ml (xl@Ml ~2^-18, dropped).
// A LDS: [var][kgrp][row^(kgrp<<1)][8] (XOR keeps b128 phases conflict-free).
// B LDS: [var][kgrp][col][8], staged linearly via global_load_lds from Bprep.
// ---------------------------------------------------------------------------
__global__ __launch_bounds__(256)
void main_mfma(const float4* __restrict__ x4,
               const float* __restrict__ scl,
               const float* __restrict__ sft,
               const __bf16* __restrict__ Bprep,
               const float* __restrict__ cvec,
               float* __restrict__ out,
               float4* __restrict__ rf4) {
    __shared__ __align__(16) __bf16 Abuf[2][4][64][8];    // 8 KB
    __shared__ __align__(16) __bf16 Bbuf[2][4][256][8];   // 32 KB
    __shared__ float ss[256], sh[256];
    int t = threadIdx.x;
    int l = t & 63;
    int w = t >> 6;
    ss[t] = scl[t];
    sh[t] = sft[t];
    size_t row0 = (size_t)blockIdx.x * 64;
    int arow = t >> 2;   // staging row 0..63
    int akg  = t & 3;    // staging kgrp 0..3

    f32x4 acc[4][4];
    #pragma unroll
    for (int i = 0; i < 4; ++i)
        #pragma unroll
        for (int j = 0; j < 4; ++j)
            acc[i][j] = (f32x4){0.f, 0.f, 0.f, 0.f};
    __syncthreads();

    int g = l >> 4, li = l & 15;
    for (int s = 0; s < 8; ++s) {
        // --- B stage: 2048 16B slots via global_load_lds (linear both sides) ---
        const __bf16* bsrc = Bprep + (size_t)s * 16384;
        __bf16* bdst = &Bbuf[0][0][0][0];
        #pragma unroll
        for (int c = 0; c < 8; ++c) {
            int slot = c * 256 + t;
            gload_lds16(bsrc + (size_t)slot * 8, bdst + (size_t)slot * 8);
        }
        // --- A stage: load x, BN, tanh->rf, split hi/lo -> LDS ---
        size_t xbase = (row0 + arow) * 64 + s * 8 + akg * 2;
        float4 v0 = x4[xbase];
        float4 v1 = x4[xbase + 1];
        int kb = s * 32 + akg * 8;
        float xn[8];
        xn[0] = v0.x * ss[kb + 0] + sh[kb + 0];
        xn[1] = v0.y * ss[kb + 1] + sh[kb + 1];
        xn[2] = v0.z * ss[kb + 2] + sh[kb + 2];
        xn[3] = v0.w * ss[kb + 3] + sh[kb + 3];
        xn[4] = v1.x * ss[kb + 4] + sh[kb + 4];
        xn[5] = v1.y * ss[kb + 5] + sh[kb + 5];
        xn[6] = v1.z * ss[kb + 6] + sh[kb + 6];
        xn[7] = v1.w * ss[kb + 7] + sh[kb + 7];
        float4 r0, r1;
        r0.x = fast_tanh(xn[0]); r0.y = fast_tanh(xn[1]);
        r0.z = fast_tanh(xn[2]); r0.w = fast_tanh(xn[3]);
        r1.x = fast_tanh(xn[4]); r1.y = fast_tanh(xn[5]);
        r1.z = fast_tanh(xn[6]); r1.w = fast_tanh(xn[7]);
        rf4[xbase] = r0;
        rf4[xbase + 1] = r1;
        bf16x8 hv, lv;
        #pragma unroll
        for (int e = 0; e < 8; ++e) {
            __bf16 h = (__bf16)xn[e];
            hv[e] = h;
            lv[e] = (__bf16)(xn[e] - (float)h);
        }
        int rx = arow ^ (akg << 1);
        *(bf16x8*)&Abuf[0][akg][rx][0] = hv;
        *(bf16x8*)&Abuf[1][akg][rx][0] = lv;
        __syncthreads();

        // --- compute: per wave 8 A-frag reads, 8 B-frag reads, 48 MFMA ---
        bf16x8 ah[4], al[4];
        #pragma unroll
        for (int i = 0; i < 4; ++i) {
            int rxr = (i * 16 + li) ^ (g << 1);
            ah[i] = *(const bf16x8*)&Abuf[0][g][rxr][0];
            al[i] = *(const bf16x8*)&Abuf[1][g][rxr][0];
        }
        #pragma unroll
        for (int j = 0; j < 4; ++j) {
            int coll = w * 64 + j * 16 + li;
            bf16x8 bh = *(const bf16x8*)&Bbuf[0][g][coll][0];
            bf16x8 bl = *(const bf16x8*)&Bbuf[1][g][coll][0];
            #pragma unroll
            for (int i = 0; i < 4; ++i) {
                acc[i][j] = __builtin_amdgcn_mfma_f32_16x16x32_bf16(ah[i], bh, acc[i][j], 0, 0, 0);
                acc[i][j] = __builtin_amdgcn_mfma_f32_16x16x32_bf16(al[i], bh, acc[i][j], 0, 0, 0);
                acc[i][j] = __builtin_amdgcn_mfma_f32_16x16x32_bf16(ah[i], bl, acc[i][j], 0, 0, 0);
            }
        }
        __syncthreads();
    }

    // --- epilogue: out = tanh(acc + c), C/D map: col=lane&15, row=(lane>>4)*4+reg ---
    #pragma unroll
    for (int j = 0; j < 4; ++j) {
        int gcol = w * 64 + j * 16 + li;
        float cj = cvec[gcol];
        #pragma unroll
        for (int i = 0; i < 4; ++i) {
            #pragma unroll
            for (int r = 0; r < 4; ++r) {
                size_t grow = row0 + i * 16 + g * 4 + r;
                out[grow * 256 + gcol] = fast_tanh(acc[i][j][r] + cj);
            }
        }
    }
}

// ---------------------------------------------------------------------------
// ws layout (floats):
//   [0]      sums   256
//   [256]    sumsq  256
//   [512]    P      131072     (zeroed: atomic split-K target)
//   [131584] u      2048
//   [133632] cv     256
//   [133888] scl    256
//   [134144] sft    256
//   [134400] Bprep  (as __bf16, 131072 elems = 65536 float slots)
// total 199936 floats ~= 800 KB.
// ---------------------------------------------------------------------------
extern "C" void kernel_launch(void* const* d_in, const int* in_sizes, int n_in,
                              void* d_out, int out_size, void* d_ws, size_t ws_size,
                              hipStream_t stream) {
    const float* x     = (const float*)d_in[0];
    const float* gamma = (const float*)d_in[1];
    const float* beta  = (const float*)d_in[2];
    const float* W1    = (const float*)d_in[3];
    const float* b1    = (const float*)d_in[4];
    const float* W2    = (const float*)d_in[5];
    const float* b2    = (const float*)d_in[6];
    const float* Wf    = (const float*)d_in[7];
    const float* bf    = (const float*)d_in[8];

    float* out = (float*)d_out;                    // [65536,256]
    float* rf  = out + (size_t)NROWS * DFEAT;      // [65536,256]

    float* ws    = (float*)d_ws;
    float* sums  = ws;
    float* sumsq = ws + 256;
    float* P     = ws + 512;
    float* u     = ws + 131584;
    float* cv    = ws + 133632;
    float* scl   = ws + 133888;
    float* sft   = ws + 134144;
    __bf16* Bprep = (__bf16*)(ws + 134400);

    // zero atomic targets: sums, sumsq, P
    hipMemsetAsync(ws, 0, (size_t)131584 * sizeof(float), stream);

    stats_kernel<<<512, 256, 0, stream>>>((const float4*)x, sums, sumsq);
    finalize_mvu_kernel<<<513, 256, 0, stream>>>(sums, sumsq, gamma, beta,
                                                 scl, sft, W2, b1, b2, u);
    pgemm_kernel<<<dim3(512 / 32, 256 / 32, 4), 256, 0, stream>>>(Wf, W2, P);
    collapse2_kernel<<<128, 256, 0, stream>>>(P, W1, Wf, u, bf, Bprep, cv);
    main_mfma<<<NROWS / 64, 256, 0, stream>>>((const float4*)x, scl, sft,
                                              Bprep, cv, out, (float4*)rf);
}

// Round 4
// 258.494 us; speedup vs baseline: 1.3903x; 1.1043x over previous
//
#include <hip/hip_runtime.h>
#include <hip/hip_bf16.h>
#include <stdint.h>

#define NROWS 65536
#define DFEAT 256

typedef __bf16 bf16x8 __attribute__((ext_vector_type(8)));
typedef float f32x4 __attribute__((ext_vector_type(4)));

__device__ __forceinline__ float fast_tanh(float x) {
    return 1.0f - 2.0f / (__expf(2.0f * x) + 1.0f);
}

// ---------------------------------------------------------------------------
// K1 (merged, all parts independent):
//   blocks [0,512):    per-column sum/sumsq of x (atomics into zeroed ws)
//   blocks [512,1024): P = Wf@W2 [256,512], K=2048, split-K=4, fp32 atomics
//   blocks [1024,1536): u = W2@b1 + b2 [2048]
// ---------------------------------------------------------------------------
__global__ void k1_kernel(const float4* __restrict__ x4,
                          float* __restrict__ sums,
                          float* __restrict__ sumsq,
                          const float* __restrict__ Wf,
                          const float* __restrict__ W2,
                          const float* __restrict__ b1,
                          const float* __restrict__ b2,
                          float* __restrict__ P,
                          float* __restrict__ u) {
    __shared__ float smem[2176];
    int t = threadIdx.x;
    int b = blockIdx.x;
    if (b < 512) {
        // ---- stats ----
        float (*ps)[256] = (float (*)[256])smem;          // [4][256]
        float (*pq)[256] = (float (*)[256])(smem + 1024); // [4][256]
        int c4 = t & 63;
        int r  = t >> 6;
        size_t i0 = (size_t)b * 128;
        float4 s = make_float4(0.f, 0.f, 0.f, 0.f);
        float4 q = make_float4(0.f, 0.f, 0.f, 0.f);
        for (int i = r; i < 128; i += 4) {
            float4 v = x4[(i0 + i) * 64 + c4];
            s.x += v.x; s.y += v.y; s.z += v.z; s.w += v.w;
            q.x += v.x * v.x; q.y += v.y * v.y; q.z += v.z * v.z; q.w += v.w * v.w;
        }
        ps[r][c4 * 4 + 0] = s.x; ps[r][c4 * 4 + 1] = s.y;
        ps[r][c4 * 4 + 2] = s.z; ps[r][c4 * 4 + 3] = s.w;
        pq[r][c4 * 4 + 0] = q.x; pq[r][c4 * 4 + 1] = q.y;
        pq[r][c4 * 4 + 2] = q.z; pq[r][c4 * 4 + 3] = q.w;
        __syncthreads();
        float ts = ps[0][t] + ps[1][t] + ps[2][t] + ps[3][t];
        float tq = pq[0][t] + pq[1][t] + pq[2][t] + pq[3][t];
        atomicAdd(&sums[t], ts);
        atomicAdd(&sumsq[t], tq);
    } else if (b < 1024) {
        // ---- P = Wf@W2, split-K ----
        int bb = b - 512;
        int bj = (bb & 15) * 32;        // N dim (512)
        int bi = ((bb >> 4) & 7) * 32;  // M dim (256)
        int kb = (bb >> 7) * 512;       // K chunk
        float (*As)[33] = (float (*)[33])smem;          // [32][33]
        float (*Bs)[33] = (float (*)[33])(smem + 1056); // [32][33]
        int tx = t & 15, ty = t >> 4;
        int row = t >> 3;
        int col = (t & 7) * 4;
        float acc00 = 0.f, acc01 = 0.f, acc10 = 0.f, acc11 = 0.f;
        for (int k0 = kb; k0 < kb + 512; k0 += 32) {
            float4 av = *(const float4*)&Wf[(size_t)(bi + row) * 2048 + k0 + col];
            As[row][col + 0] = av.x; As[row][col + 1] = av.y;
            As[row][col + 2] = av.z; As[row][col + 3] = av.w;
            float4 bv = *(const float4*)&W2[(size_t)(k0 + row) * 512 + bj + col];
            Bs[row][col + 0] = bv.x; Bs[row][col + 1] = bv.y;
            Bs[row][col + 2] = bv.z; Bs[row][col + 3] = bv.w;
            __syncthreads();
            #pragma unroll
            for (int k = 0; k < 32; ++k) {
                float a0 = As[ty * 2 + 0][k];
                float a1 = As[ty * 2 + 1][k];
                float b0 = Bs[k][tx * 2 + 0];
                float b1v = Bs[k][tx * 2 + 1];
                acc00 += a0 * b0; acc01 += a0 * b1v;
                acc10 += a1 * b0; acc11 += a1 * b1v;
            }
            __syncthreads();
        }
        int i = bi + ty * 2, j = bj + tx * 2;
        atomicAdd(&P[(size_t)(i + 0) * 512 + j + 0], acc00);
        atomicAdd(&P[(size_t)(i + 0) * 512 + j + 1], acc01);
        atomicAdd(&P[(size_t)(i + 1) * 512 + j + 0], acc10);
        atomicAdd(&P[(size_t)(i + 1) * 512 + j + 1], acc11);
    } else {
        // ---- u = W2@b1 + b2 ----
        int lane = t & 63;
        int row = (b - 1024) * 4 + (t >> 6);
        const float* Wr = W2 + (size_t)row * 512;
        float s = 0.f;
        for (int k = lane; k < 512; k += 64) s += Wr[k] * b1[k];
        #pragma unroll
        for (int off = 32; off; off >>= 1) s += __shfl_xor(s, off);
        if (lane == 0) u[row] = s + b2[row];
    }
}

// ---------------------------------------------------------------------------
// K2 (merged, all parts depend only on K1):
//   blocks [0,64):   M = P@W1, epilogue -> bf16 hi/lo Bprep[8][2][4][256][8]
//   blocks [64,128): cv = Wf@u + bf
//   block 128:       finalize BN -> scl/sft
// ---------------------------------------------------------------------------
__global__ void k2_kernel(const float* __restrict__ sums,
                          const float* __restrict__ sumsq,
                          const float* __restrict__ gamma,
                          const float* __restrict__ beta,
                          float* __restrict__ scl,
                          float* __restrict__ sft,
                          const float* __restrict__ P,
                          const float* __restrict__ W1,
                          const float* __restrict__ Wf,
                          const float* __restrict__ u,
                          const float* __restrict__ bfv,
                          __bf16* __restrict__ Bprep,
                          float* __restrict__ cv) {
    __shared__ float smem[2176];
    int t = threadIdx.x;
    int b = blockIdx.x;
    if (b >= 128) {
        const float invN = 1.0f / (float)NROWS;
        float mu  = sums[t] * invN;
        float var = sumsq[t] * invN - mu * mu;
        float rs  = rsqrtf(var + 1e-5f);
        float a   = gamma[t] * rs;
        scl[t] = a;
        sft[t] = beta[t] - mu * a;
        return;
    }
    if (b >= 64) {
        int lane = t & 63;
        int row = (b - 64) * 4 + (t >> 6);
        const float* Wr = Wf + (size_t)row * 2048;
        float s = 0.f;
        for (int k = lane; k < 2048; k += 64) s += Wr[k] * u[k];
        #pragma unroll
        for (int off = 32; off; off >>= 1) s += __shfl_xor(s, off);
        if (lane == 0) cv[row] = s + bfv[row];
        return;
    }
    // ---- M tile + Bprep ----
    float (*As)[33] = (float (*)[33])smem;
    float (*Bs)[33] = (float (*)[33])(smem + 1056);
    int tx = t & 15, ty = t >> 4;
    int bi = (b >> 3) * 32;   // j-dim of M (output col of main GEMM)
    int bj = (b & 7) * 32;    // k-dim of M
    int row = t >> 3;
    int col = (t & 7) * 4;
    float acc00 = 0.f, acc01 = 0.f, acc10 = 0.f, acc11 = 0.f;
    for (int k0 = 0; k0 < 512; k0 += 32) {
        float4 av = *(const float4*)&P[(size_t)(bi + row) * 512 + k0 + col];
        As[row][col + 0] = av.x; As[row][col + 1] = av.y;
        As[row][col + 2] = av.z; As[row][col + 3] = av.w;
        float4 bv = *(const float4*)&W1[(size_t)(k0 + row) * 256 + bj + col];
        Bs[row][col + 0] = bv.x; Bs[row][col + 1] = bv.y;
        Bs[row][col + 2] = bv.z; Bs[row][col + 3] = bv.w;
        __syncthreads();
        #pragma unroll
        for (int k = 0; k < 32; ++k) {
            float a0 = As[ty * 2 + 0][k];
            float a1 = As[ty * 2 + 1][k];
            float b0 = Bs[k][tx * 2 + 0];
            float b1v = Bs[k][tx * 2 + 1];
            acc00 += a0 * b0; acc01 += a0 * b1v;
            acc10 += a1 * b0; acc11 += a1 * b1v;
        }
        __syncthreads();
    }
    int j = bi + ty * 2, k = bj + tx * 2;
    float vals[2][2] = {{acc00, acc01}, {acc10, acc11}};
    #pragma unroll
    for (int dj = 0; dj < 2; ++dj)
        #pragma unroll
        for (int dk = 0; dk < 2; ++dk) {
            float v = vals[dj][dk];
            int jj = j + dj, kk = k + dk;
            __bf16 h = (__bf16)v;
            __bf16 lo = (__bf16)(v - (float)h);
            int kstep = kk >> 5, kgrp = (kk >> 3) & 3, e = kk & 7;
            Bprep[((((size_t)kstep * 2 + 0) * 4 + kgrp) * 256 + jj) * 8 + e] = h;
            Bprep[((((size_t)kstep * 2 + 1) * 4 + kgrp) * 256 + jj) * 8 + e] = lo;
        }
}

// ---------------------------------------------------------------------------
// Main: fused BN + raw_feats + split-bf16 MFMA GEMM + tanh.
// 256 threads = 4 waves, BM=64 rows, BN=256 cols, BK=32, 8 K-steps.
// A (xn hi/lo) staged in 8 KB LDS, layout [var][row][kgrp][8] (bank-uniform:
// every b128 read/write covers all 32 banks exactly 8x).
// B fragments read DIRECTLY from global (Bprep is 256 KB -> L2-resident);
// no global_load_lds -> no vmcnt(0) barrier drains, small LDS -> 4 blocks/CU.
// 3 passes: xh@Mh + xl@Mh + xh@Ml (xl@Ml ~2^-18, dropped).
// ---------------------------------------------------------------------------
__global__ __launch_bounds__(256, 4)
void main_mfma(const float4* __restrict__ x4,
               const float4* __restrict__ scl4,
               const float4* __restrict__ sft4,
               const __bf16* __restrict__ Bprep,
               const float* __restrict__ cvec,
               float* __restrict__ out,
               float4* __restrict__ rf4) {
    __shared__ __align__(16) __bf16 Abuf[2][64][4][8];   // 8 KB
    int t = threadIdx.x;
    int l = t & 63;
    int w = t >> 6;
    int g = l >> 4, li = l & 15;
    size_t row0 = (size_t)blockIdx.x * 64;
    int arow = t >> 2;   // staging row 0..63
    int akg  = t & 3;    // staging kgrp 0..3

    f32x4 acc[4][4];
    #pragma unroll
    for (int i = 0; i < 4; ++i)
        #pragma unroll
        for (int j = 0; j < 4; ++j)
            acc[i][j] = (f32x4){0.f, 0.f, 0.f, 0.f};

    for (int s = 0; s < 8; ++s) {
        // --- A stage: load x, BN, tanh->rf, split hi/lo -> LDS ---
        size_t xbase = (row0 + arow) * 64 + s * 8 + akg * 2;
        float4 v0 = x4[xbase];
        float4 v1 = x4[xbase + 1];
        int kb4 = s * 8 + akg * 2;           // float4 index into scl/sft
        float4 sc0 = scl4[kb4], sc1 = scl4[kb4 + 1];
        float4 sf0 = sft4[kb4], sf1 = sft4[kb4 + 1];
        float xn[8];
        xn[0] = v0.x * sc0.x + sf0.x;
        xn[1] = v0.y * sc0.y + sf0.y;
        xn[2] = v0.z * sc0.z + sf0.z;
        xn[3] = v0.w * sc0.w + sf0.w;
        xn[4] = v1.x * sc1.x + sf1.x;
        xn[5] = v1.y * sc1.y + sf1.y;
        xn[6] = v1.z * sc1.z + sf1.z;
        xn[7] = v1.w * sc1.w + sf1.w;
        float4 r0, r1;
        r0.x = fast_tanh(xn[0]); r0.y = fast_tanh(xn[1]);
        r0.z = fast_tanh(xn[2]); r0.w = fast_tanh(xn[3]);
        r1.x = fast_tanh(xn[4]); r1.y = fast_tanh(xn[5]);
        r1.z = fast_tanh(xn[6]); r1.w = fast_tanh(xn[7]);
        rf4[xbase] = r0;
        rf4[xbase + 1] = r1;
        bf16x8 hv, lv;
        #pragma unroll
        for (int e = 0; e < 8; ++e) {
            __bf16 h = (__bf16)xn[e];
            hv[e] = h;
            lv[e] = (__bf16)(xn[e] - (float)h);
        }
        *(bf16x8*)&Abuf[0][arow][akg][0] = hv;
        *(bf16x8*)&Abuf[1][arow][akg][0] = lv;
        __syncthreads();

        // --- A fragments from LDS ---
        bf16x8 ah[4], al[4];
        #pragma unroll
        for (int i = 0; i < 4; ++i) {
            ah[i] = *(const bf16x8*)&Abuf[0][i * 16 + li][g][0];
            al[i] = *(const bf16x8*)&Abuf[1][i * 16 + li][g][0];
        }
        // --- B fragments direct from global (L2-resident), then MFMA ---
        const __bf16* bh_base = Bprep + (size_t)(8 * s + g) * 2048;
        const __bf16* bl_base = Bprep + (size_t)(8 * s + 4 + g) * 2048;
        #pragma unroll
        for (int j = 0; j < 4; ++j) {
            int coll = w * 64 + j * 16 + li;
            bf16x8 bh = *(const bf16x8*)&bh_base[(size_t)coll * 8];
            bf16x8 bl = *(const bf16x8*)&bl_base[(size_t)coll * 8];
            #pragma unroll
            for (int i = 0; i < 4; ++i) {
                acc[i][j] = __builtin_amdgcn_mfma_f32_16x16x32_bf16(ah[i], bh, acc[i][j], 0, 0, 0);
                acc[i][j] = __builtin_amdgcn_mfma_f32_16x16x32_bf16(al[i], bh, acc[i][j], 0, 0, 0);
                acc[i][j] = __builtin_amdgcn_mfma_f32_16x16x32_bf16(ah[i], bl, acc[i][j], 0, 0, 0);
            }
        }
        __syncthreads();
    }

    // --- epilogue: out = tanh(acc + c); C/D map col=lane&15, row=(lane>>4)*4+reg ---
    #pragma unroll
    for (int j = 0; j < 4; ++j) {
        int gcol = w * 64 + j * 16 + li;
        float cj = cvec[gcol];
        #pragma unroll
        for (int i = 0; i < 4; ++i) {
            #pragma unroll
            for (int r = 0; r < 4; ++r) {
                size_t grow = row0 + i * 16 + g * 4 + r;
                out[grow * 256 + gcol] = fast_tanh(acc[i][j][r] + cj);
            }
        }
    }
}

// ---------------------------------------------------------------------------
// ws layout (floats):
//   [0]      sums   256      (zeroed)
//   [256]    sumsq  256      (zeroed)
//   [512]    P      131072   (zeroed: atomic split-K target)
//   [131584] u      2048
//   [133632] cv     256
//   [133888] scl    256
//   [134144] sft    256
//   [134400] Bprep  (__bf16, 131072 elems = 65536 float slots)
// total 199936 floats ~= 800 KB.
// ---------------------------------------------------------------------------
extern "C" void kernel_launch(void* const* d_in, const int* in_sizes, int n_in,
                              void* d_out, int out_size, void* d_ws, size_t ws_size,
                              hipStream_t stream) {
    const float* x     = (const float*)d_in[0];
    const float* gamma = (const float*)d_in[1];
    const float* beta  = (const float*)d_in[2];
    const float* W1    = (const float*)d_in[3];
    const float* b1    = (const float*)d_in[4];
    const float* W2    = (const float*)d_in[5];
    const float* b2    = (const float*)d_in[6];
    const float* Wf    = (const float*)d_in[7];
    const float* bf    = (const float*)d_in[8];

    float* out = (float*)d_out;                    // [65536,256]
    float* rf  = out + (size_t)NROWS * DFEAT;      // [65536,256]

    float* ws    = (float*)d_ws;
    float* sums  = ws;
    float* sumsq = ws + 256;
    float* P     = ws + 512;
    float* u     = ws + 131584;
    float* cv    = ws + 133632;
    float* scl   = ws + 133888;
    float* sft   = ws + 134144;
    __bf16* Bprep = (__bf16*)(ws + 134400);

    // zero atomic targets: sums, sumsq, P
    hipMemsetAsync(ws, 0, (size_t)131584 * sizeof(float), stream);

    k1_kernel<<<1536, 256, 0, stream>>>((const float4*)x, sums, sumsq,
                                        Wf, W2, b1, b2, P, u);
    k2_kernel<<<129, 256, 0, stream>>>(sums, sumsq, gamma, beta, scl, sft,
                                       P, W1, Wf, u, bf, Bprep, cv);
    main_mfma<<<NROWS / 64, 256, 0, stream>>>((const float4*)x,
                                              (const float4*)scl,
                                              (const float4*)sft,
                                              Bprep, cv, out, (float4*)rf);
}